// Round 1
// baseline (639.268 us; speedup 1.0000x reference)
//
#include <hip/hip_runtime.h>
#include <math.h>

#define EPSV 1e-6f
#define MINEIG 1e-4f

// ---------- small 3x3 helpers (all in registers) ----------

__device__ __forceinline__ void mm3(const float a[3][3], const float b[3][3], float c[3][3]) {
#pragma unroll
  for (int i = 0; i < 3; ++i)
#pragma unroll
    for (int j = 0; j < 3; ++j)
      c[i][j] = fmaf(a[i][0], b[0][j], fmaf(a[i][1], b[1][j], a[i][2] * b[2][j]));
}

__device__ __forceinline__ void inv3(const float a[3][3], float inv[3][3]) {
  float c00 = a[1][1] * a[2][2] - a[1][2] * a[2][1];
  float c01 = -(a[1][0] * a[2][2] - a[1][2] * a[2][0]);
  float c02 = a[1][0] * a[2][1] - a[1][1] * a[2][0];
  float det = a[0][0] * c00 + a[0][1] * c01 + a[0][2] * c02;
  float id = 1.0f / det;
  inv[0][0] = c00 * id;
  inv[0][1] = (a[0][2] * a[2][1] - a[0][1] * a[2][2]) * id;
  inv[0][2] = (a[0][1] * a[1][2] - a[0][2] * a[1][1]) * id;
  inv[1][0] = c01 * id;
  inv[1][1] = (a[0][0] * a[2][2] - a[0][2] * a[2][0]) * id;
  inv[1][2] = (a[0][2] * a[1][0] - a[0][0] * a[1][2]) * id;
  inv[2][0] = c02 * id;
  inv[2][1] = (a[0][1] * a[2][0] - a[0][0] * a[2][1]) * id;
  inv[2][2] = (a[0][0] * a[1][1] - a[0][1] * a[1][0]) * id;
}

// Matches reference _expm: scale by 2^-6, 12-term Taylor, 6 squarings.
__device__ void expm3(const float A[3][3], float E[3][3]) {
  float As[3][3], term[3][3], tmp[3][3];
#pragma unroll
  for (int i = 0; i < 3; ++i)
#pragma unroll
    for (int j = 0; j < 3; ++j) {
      As[i][j] = A[i][j] * (1.0f / 64.0f);
      term[i][j] = As[i][j];
      E[i][j] = ((i == j) ? 1.0f : 0.0f) + As[i][j];
    }
  for (int k = 2; k <= 12; ++k) {
    mm3(term, As, tmp);
    float r = 1.0f / (float)k;
#pragma unroll
    for (int i = 0; i < 3; ++i)
#pragma unroll
      for (int j = 0; j < 3; ++j) {
        term[i][j] = tmp[i][j] * r;
        E[i][j] += term[i][j];
      }
  }
  for (int s = 0; s < 6; ++s) {
    mm3(E, E, tmp);
#pragma unroll
    for (int i = 0; i < 3; ++i)
#pragma unroll
      for (int j = 0; j < 3; ++j) E[i][j] = tmp[i][j];
  }
}

// One cyclic-Jacobi rotation in plane (P,Q), via explicit 3x3 matmuls.
template <int P, int Q>
__device__ __forceinline__ void jrot(float A[3][3], float V[3][3]) {
  float apq = A[P][Q];
  if (fabsf(apq) < 1e-20f) return;
  float theta = (A[Q][Q] - A[P][P]) / (2.0f * apq);
  float t = copysignf(1.0f, theta) / (fabsf(theta) + sqrtf(fmaf(theta, theta, 1.0f)));
  float c = 1.0f / sqrtf(fmaf(t, t, 1.0f));
  float s = t * c;
  float J[3][3] = {{1, 0, 0}, {0, 1, 0}, {0, 0, 1}};
  J[P][P] = c; J[Q][Q] = c; J[P][Q] = s; J[Q][P] = -s;
  float Jt[3][3];
#pragma unroll
  for (int i = 0; i < 3; ++i)
#pragma unroll
    for (int j = 0; j < 3; ++j) Jt[i][j] = J[j][i];
  float tmp[3][3], A2[3][3];
  mm3(A, J, tmp);
  mm3(Jt, tmp, A2);
#pragma unroll
  for (int i = 0; i < 3; ++i)
#pragma unroll
    for (int j = 0; j < 3; ++j) A[i][j] = A2[i][j];
  mm3(V, J, tmp);
#pragma unroll
  for (int i = 0; i < 3; ++i)
#pragma unroll
    for (int j = 0; j < 3; ++j) V[i][j] = tmp[i][j];
}

__device__ __forceinline__ bool finitef(float x) {
  return !(isnan(x) || isinf(x));
}

// ---------- kernel 1: per-n prep: Lambda_p, Lambda_q, R=expm(phi_mat), S=R^T Lq R ----------

__global__ void prep_kernel(const float* __restrict__ Sp, const float* __restrict__ Sq,
                            const float* __restrict__ phi, const float* __restrict__ gen,
                            float* __restrict__ Lp, float* __restrict__ Lq,
                            float* __restrict__ Rm, float* __restrict__ Sm, int N) {
  int i = blockIdx.x * blockDim.x + threadIdx.x;
  if (i >= N) return;
  float a[3][3], lp[3][3], lq[3][3];
#pragma unroll
  for (int k = 0; k < 3; ++k)
#pragma unroll
    for (int l = 0; l < 3; ++l)
      a[k][l] = Sp[i * 9 + k * 3 + l] + ((k == l) ? EPSV : 0.0f);
  inv3(a, lp);
#pragma unroll
  for (int k = 0; k < 3; ++k)
#pragma unroll
    for (int l = 0; l < 3; ++l)
      a[k][l] = Sq[i * 9 + k * 3 + l] + ((k == l) ? EPSV : 0.0f);
  inv3(a, lq);

  float p0 = phi[i * 3 + 0], p1 = phi[i * 3 + 1], p2 = phi[i * 3 + 2];
  float A[3][3];
#pragma unroll
  for (int k = 0; k < 3; ++k)
#pragma unroll
    for (int l = 0; l < 3; ++l)
      A[k][l] = p0 * gen[0 + k * 3 + l] + p1 * gen[9 + k * 3 + l] + p2 * gen[18 + k * 3 + l];
  float R[3][3];
  expm3(A, R);
  // phi_mat is exactly skew, so expm(-phi_mat) == R^T bitwise.
  float Rt[3][3];
#pragma unroll
  for (int k = 0; k < 3; ++k)
#pragma unroll
    for (int l = 0; l < 3; ++l) Rt[k][l] = R[l][k];
  float t1[3][3], S[3][3];
  mm3(lq, R, t1);   // Lq * R
  mm3(Rt, t1, S);   // R^T * Lq * R
#pragma unroll
  for (int k = 0; k < 3; ++k)
#pragma unroll
    for (int l = 0; l < 3; ++l) {
      Lp[i * 9 + k * 3 + l] = lp[k][l];
      Lq[i * 9 + k * 3 + l] = lq[k][l];
      Rm[i * 9 + k * 3 + l] = R[k][l];
      Sm[i * 9 + k * 3 + l] = S[k][l];
    }
}

// ---------- kernel 2: Lambda_o via softmax moments over V ----------

__global__ void lambda_o_kernel(const float* __restrict__ mu, const float* __restrict__ W,
                                float* __restrict__ Lo, int V) {
  int n = blockIdx.x;
  int tid = threadIdx.x;
  float m0 = mu[n * 3 + 0], m1 = mu[n * 3 + 1], m2 = mu[n * 3 + 2];
  float se = 0.f, a0 = 0.f, a1 = 0.f, a2 = 0.f;
  float s00 = 0.f, s01 = 0.f, s02 = 0.f, s11 = 0.f, s12 = 0.f, s22 = 0.f;
  for (int v = tid; v < V; v += 256) {
    float w0 = W[v * 3 + 0], w1 = W[v * 3 + 1], w2 = W[v * 3 + 2];
    float l = fmaf(m0, w0, fmaf(m1, w1, m2 * w2));
    // logits bounded (|mu|,|w| small) -> no max-subtraction needed; exp sums
    // stay far below fp32 range, relative precision identical to ref softmax.
    float e = __expf(l);
    se += e;
    float ew0 = e * w0, ew1 = e * w1, ew2 = e * w2;
    a0 += ew0; a1 += ew1; a2 += ew2;
    s00 = fmaf(ew0, w0, s00); s01 = fmaf(ew0, w1, s01); s02 = fmaf(ew0, w2, s02);
    s11 = fmaf(ew1, w1, s11); s12 = fmaf(ew1, w2, s12); s22 = fmaf(ew2, w2, s22);
  }
  float vals[10] = {se, a0, a1, a2, s00, s01, s02, s11, s12, s22};
  __shared__ float sred[4][10];
#pragma unroll
  for (int k = 0; k < 10; ++k) {
    float x = vals[k];
#pragma unroll
    for (int o = 32; o > 0; o >>= 1) x += __shfl_down(x, o, 64);
    if ((tid & 63) == 0) sred[tid >> 6][k] = x;
  }
  __syncthreads();
  if (tid == 0) {
    float tot[10];
#pragma unroll
    for (int k = 0; k < 10; ++k)
      tot[k] = sred[0][k] + sred[1][k] + sred[2][k] + sred[3][k];
    float inv = 1.0f / tot[0];
    float mw0 = tot[1] * inv, mw1 = tot[2] * inv, mw2 = tot[3] * inv;
    float L00 = tot[4] * inv - mw0 * mw0 + EPSV;
    float L01 = tot[5] * inv - mw0 * mw1;
    float L02 = tot[6] * inv - mw0 * mw2;
    float L11 = tot[7] * inv - mw1 * mw1 + EPSV;
    float L12 = tot[8] * inv - mw1 * mw2;
    float L22 = tot[9] * inv - mw2 * mw2 + EPSV;
    float* o = Lo + n * 9;
    o[0] = L00; o[1] = L01; o[2] = L02;
    o[3] = L01; o[4] = L11; o[5] = L12;
    o[6] = L02; o[7] = L12; o[8] = L22;
  }
}

// ---------- kernel 3: column sums of beta ----------

__global__ void colsum_kernel(const float* __restrict__ beta, float* __restrict__ cs, int N) {
  int i = blockIdx.x * blockDim.x + threadIdx.x;
  if (i >= N) return;
  float s = 0.f;
  for (int j = 0; j < N; ++j) s += beta[(size_t)j * N + i];
  cs[i] = s;
}

// ---------- kernel 4: T = beta @ S  (N x N) @ (N x 9) ----------

__global__ void bmm_kernel(const float* __restrict__ beta, const float* __restrict__ S,
                           float* __restrict__ T, int N) {
  const int ROWS = 8;
  int i0 = blockIdx.x * ROWS;
  int tid = threadIdx.x;
  float acc[ROWS][9];
#pragma unroll
  for (int r = 0; r < ROWS; ++r)
#pragma unroll
    for (int k = 0; k < 9; ++k) acc[r][k] = 0.f;

  for (int jt = 0; jt < N; jt += 256) {
    int j = jt + tid;
    float sv[9];
    if (j < N) {
#pragma unroll
      for (int k = 0; k < 9; ++k) sv[k] = S[j * 9 + k];
#pragma unroll
      for (int r = 0; r < ROWS; ++r) {
        int row = i0 + r;
        if (row < N) {
          float b = beta[(size_t)row * N + j];
#pragma unroll
          for (int k = 0; k < 9; ++k) acc[r][k] = fmaf(b, sv[k], acc[r][k]);
        }
      }
    }
  }

  __shared__ float red[4][9];
  for (int r = 0; r < ROWS; ++r) {
    float part[9];
#pragma unroll
    for (int k = 0; k < 9; ++k) {
      float x = acc[r][k];
#pragma unroll
      for (int o = 32; o > 0; o >>= 1) x += __shfl_down(x, o, 64);
      part[k] = x;
    }
    if ((tid & 63) == 0) {
#pragma unroll
      for (int k = 0; k < 9; ++k) red[tid >> 6][k] = part[k];
    }
    __syncthreads();
    if (tid == 0 && (i0 + r) < N) {
#pragma unroll
      for (int k = 0; k < 9; ++k)
        T[(i0 + r) * 9 + k] = red[0][k] + red[1][k] + red[2][k] + red[3][k];
    }
    __syncthreads();
  }
}

// ---------- kernel 5: assemble M, Jacobi eigh, floor, reconstruct ----------

__global__ void finalize_kernel(const float* __restrict__ Lp, const float* __restrict__ Lq,
                                const float* __restrict__ Rm, const float* __restrict__ Lo,
                                const float* __restrict__ T, const float* __restrict__ cs,
                                float* __restrict__ out, int N) {
  int i = blockIdx.x * blockDim.x + threadIdx.x;
  if (i >= N) return;
  float R[3][3], Tm[3][3], M[3][3];
#pragma unroll
  for (int k = 0; k < 3; ++k)
#pragma unroll
    for (int l = 0; l < 3; ++l) {
      R[k][l] = Rm[i * 9 + k * 3 + l];
      Tm[k][l] = T[i * 9 + k * 3 + l];
    }
  float t1[3][3], Rt[3][3], Min[3][3];
  mm3(R, Tm, t1);
#pragma unroll
  for (int k = 0; k < 3; ++k)
#pragma unroll
    for (int l = 0; l < 3; ++l) Rt[k][l] = R[l][k];
  mm3(t1, Rt, Min);
  float c = cs[i];
#pragma unroll
  for (int k = 0; k < 3; ++k)
#pragma unroll
    for (int l = 0; l < 3; ++l)
      M[k][l] = Lp[i * 9 + k * 3 + l] + Lo[i * 9 + k * 3 + l] + Min[k][l] +
                c * Lq[i * 9 + k * 3 + l];
  // symmetrize
#pragma unroll
  for (int k = 0; k < 3; ++k)
#pragma unroll
    for (int l = 0; l < 3; ++l) {
      if (l > k) {
        float v = 0.5f * (M[k][l] + M[l][k]);
        M[k][l] = v; M[l][k] = v;
      }
    }
  // non-finite -> identity entries
#pragma unroll
  for (int k = 0; k < 3; ++k)
#pragma unroll
    for (int l = 0; l < 3; ++l)
      if (!finitef(M[k][l])) M[k][l] = (k == l) ? 1.0f : 0.0f;
  M[0][0] += MINEIG; M[1][1] += MINEIG; M[2][2] += MINEIG;

  // cyclic Jacobi, 12 sweeps (overkill for 3x3, ~machine precision)
  float A[3][3], V[3][3] = {{1, 0, 0}, {0, 1, 0}, {0, 0, 1}};
#pragma unroll
  for (int k = 0; k < 3; ++k)
#pragma unroll
    for (int l = 0; l < 3; ++l) A[k][l] = M[k][l];
  for (int sweep = 0; sweep < 12; ++sweep) {
    jrot<0, 1>(A, V);
    jrot<0, 2>(A, V);
    jrot<1, 2>(A, V);
  }
  float wc[3], wi[3];
#pragma unroll
  for (int k = 0; k < 3; ++k) {
    wc[k] = fmaxf(A[k][k], MINEIG);
    wi[k] = 1.0f / wc[k];
  }
  // M_pd = V diag(wc) V^T ; M_inv = V diag(1/wc) V^T
#pragma unroll
  for (int k = 0; k < 3; ++k)
#pragma unroll
    for (int l = 0; l < 3; ++l) {
      float mpd = V[k][0] * wc[0] * V[l][0] + V[k][1] * wc[1] * V[l][1] +
                  V[k][2] * wc[2] * V[l][2];
      float mnv = V[k][0] * wi[0] * V[l][0] + V[k][1] * wi[1] * V[l][1] +
                  V[k][2] * wi[2] * V[l][2];
      out[i * 9 + k * 3 + l] = mpd;
      out[(size_t)N * 9 + i * 9 + k * 3 + l] = mnv;
    }
}

// ---------- launcher ----------

extern "C" void kernel_launch(void* const* d_in, const int* in_sizes, int n_in,
                              void* d_out, int out_size, void* d_ws, size_t ws_size,
                              hipStream_t stream) {
  const float* Sp = (const float*)d_in[0];
  const float* Sq = (const float*)d_in[1];
  const float* phi = (const float*)d_in[2];
  const float* beta = (const float*)d_in[3];
  const float* mu = (const float*)d_in[4];
  const float* W = (const float*)d_in[5];
  const float* gen = (const float*)d_in[6];
  float* out = (float*)d_out;

  const int N = in_sizes[2] / 3;   // phi is (B,N,3), B=1
  const int V = in_sizes[5] / 3;   // W_out is (V,3)

  float* ws = (float*)d_ws;
  float* Lp = ws;                // N*9
  float* Lq = Lp + (size_t)N * 9;
  float* Rm = Lq + (size_t)N * 9;
  float* Sm = Rm + (size_t)N * 9;
  float* Lo = Sm + (size_t)N * 9;
  float* T  = Lo + (size_t)N * 9;
  float* cs = T + (size_t)N * 9;  // N

  int nb = (N + 255) / 256;
  prep_kernel<<<nb, 256, 0, stream>>>(Sp, Sq, phi, gen, Lp, Lq, Rm, Sm, N);
  lambda_o_kernel<<<N, 256, 0, stream>>>(mu, W, Lo, V);
  colsum_kernel<<<nb, 256, 0, stream>>>(beta, cs, N);
  bmm_kernel<<<(N + 7) / 8, 256, 0, stream>>>(beta, Sm, T, N);
  finalize_kernel<<<nb, 256, 0, stream>>>(Lp, Lq, Rm, Lo, T, cs, out, N);
}

// Round 2
// 156.256 us; speedup vs baseline: 4.0911x; 4.0911x over previous
//
#include <hip/hip_runtime.h>
#include <math.h>

#define EPSV 1e-6f
#define MINEIG 1e-4f

// ---------- small 3x3 helpers (all in registers) ----------

__device__ __forceinline__ void mm3(const float a[3][3], const float b[3][3], float c[3][3]) {
#pragma unroll
  for (int i = 0; i < 3; ++i)
#pragma unroll
    for (int j = 0; j < 3; ++j)
      c[i][j] = fmaf(a[i][0], b[0][j], fmaf(a[i][1], b[1][j], a[i][2] * b[2][j]));
}

__device__ __forceinline__ void inv3(const float a[3][3], float inv[3][3]) {
  float c00 = a[1][1] * a[2][2] - a[1][2] * a[2][1];
  float c01 = -(a[1][0] * a[2][2] - a[1][2] * a[2][0]);
  float c02 = a[1][0] * a[2][1] - a[1][1] * a[2][0];
  float det = a[0][0] * c00 + a[0][1] * c01 + a[0][2] * c02;
  float id = 1.0f / det;
  inv[0][0] = c00 * id;
  inv[0][1] = (a[0][2] * a[2][1] - a[0][1] * a[2][2]) * id;
  inv[0][2] = (a[0][1] * a[1][2] - a[0][2] * a[1][1]) * id;
  inv[1][0] = c01 * id;
  inv[1][1] = (a[0][0] * a[2][2] - a[0][2] * a[2][0]) * id;
  inv[1][2] = (a[0][2] * a[1][0] - a[0][0] * a[1][2]) * id;
  inv[2][0] = c02 * id;
  inv[2][1] = (a[0][1] * a[2][0] - a[0][0] * a[2][1]) * id;
  inv[2][2] = (a[0][0] * a[1][1] - a[0][1] * a[1][0]) * id;
}

// Matches reference _expm: scale by 2^-6, 12-term Taylor, 6 squarings.
__device__ void expm3(const float A[3][3], float E[3][3]) {
  float As[3][3], term[3][3], tmp[3][3];
#pragma unroll
  for (int i = 0; i < 3; ++i)
#pragma unroll
    for (int j = 0; j < 3; ++j) {
      As[i][j] = A[i][j] * (1.0f / 64.0f);
      term[i][j] = As[i][j];
      E[i][j] = ((i == j) ? 1.0f : 0.0f) + As[i][j];
    }
  for (int k = 2; k <= 12; ++k) {
    mm3(term, As, tmp);
    float r = 1.0f / (float)k;
#pragma unroll
    for (int i = 0; i < 3; ++i)
#pragma unroll
      for (int j = 0; j < 3; ++j) {
        term[i][j] = tmp[i][j] * r;
        E[i][j] += term[i][j];
      }
  }
  for (int s = 0; s < 6; ++s) {
    mm3(E, E, tmp);
#pragma unroll
    for (int i = 0; i < 3; ++i)
#pragma unroll
      for (int j = 0; j < 3; ++j) E[i][j] = tmp[i][j];
  }
}

// One cyclic-Jacobi rotation in plane (P,Q), via explicit 3x3 matmuls.
template <int P, int Q>
__device__ __forceinline__ void jrot(float A[3][3], float V[3][3]) {
  float apq = A[P][Q];
  if (fabsf(apq) < 1e-20f) return;
  float theta = (A[Q][Q] - A[P][P]) / (2.0f * apq);
  float t = copysignf(1.0f, theta) / (fabsf(theta) + sqrtf(fmaf(theta, theta, 1.0f)));
  float c = 1.0f / sqrtf(fmaf(t, t, 1.0f));
  float s = t * c;
  float J[3][3] = {{1, 0, 0}, {0, 1, 0}, {0, 0, 1}};
  J[P][P] = c; J[Q][Q] = c; J[P][Q] = s; J[Q][P] = -s;
  float Jt[3][3];
#pragma unroll
  for (int i = 0; i < 3; ++i)
#pragma unroll
    for (int j = 0; j < 3; ++j) Jt[i][j] = J[j][i];
  float tmp[3][3], A2[3][3];
  mm3(A, J, tmp);
  mm3(Jt, tmp, A2);
#pragma unroll
  for (int i = 0; i < 3; ++i)
#pragma unroll
    for (int j = 0; j < 3; ++j) A[i][j] = A2[i][j];
  mm3(V, J, tmp);
#pragma unroll
  for (int i = 0; i < 3; ++i)
#pragma unroll
    for (int j = 0; j < 3; ++j) V[i][j] = tmp[i][j];
}

__device__ __forceinline__ bool finitef(float x) {
  return !(isnan(x) || isinf(x));
}

// ---------- kernel 1: per-n prep: Lambda_p, Lambda_q, R=expm(phi_mat), S=R^T Lq R ----------

__global__ void prep_kernel(const float* __restrict__ Sp, const float* __restrict__ Sq,
                            const float* __restrict__ phi, const float* __restrict__ gen,
                            float* __restrict__ Lp, float* __restrict__ Lq,
                            float* __restrict__ Rm, float* __restrict__ Sm, int N) {
  int i = blockIdx.x * blockDim.x + threadIdx.x;
  if (i >= N) return;
  float a[3][3], lp[3][3], lq[3][3];
#pragma unroll
  for (int k = 0; k < 3; ++k)
#pragma unroll
    for (int l = 0; l < 3; ++l)
      a[k][l] = Sp[i * 9 + k * 3 + l] + ((k == l) ? EPSV : 0.0f);
  inv3(a, lp);
#pragma unroll
  for (int k = 0; k < 3; ++k)
#pragma unroll
    for (int l = 0; l < 3; ++l)
      a[k][l] = Sq[i * 9 + k * 3 + l] + ((k == l) ? EPSV : 0.0f);
  inv3(a, lq);

  float p0 = phi[i * 3 + 0], p1 = phi[i * 3 + 1], p2 = phi[i * 3 + 2];
  float A[3][3];
#pragma unroll
  for (int k = 0; k < 3; ++k)
#pragma unroll
    for (int l = 0; l < 3; ++l)
      A[k][l] = p0 * gen[0 + k * 3 + l] + p1 * gen[9 + k * 3 + l] + p2 * gen[18 + k * 3 + l];
  float R[3][3];
  expm3(A, R);
  // phi_mat is exactly skew, so expm(-phi_mat) == R^T bitwise.
  float Rt[3][3];
#pragma unroll
  for (int k = 0; k < 3; ++k)
#pragma unroll
    for (int l = 0; l < 3; ++l) Rt[k][l] = R[l][k];
  float t1[3][3], S[3][3];
  mm3(lq, R, t1);   // Lq * R
  mm3(Rt, t1, S);   // R^T * Lq * R
#pragma unroll
  for (int k = 0; k < 3; ++k)
#pragma unroll
    for (int l = 0; l < 3; ++l) {
      Lp[i * 9 + k * 3 + l] = lp[k][l];
      Lq[i * 9 + k * 3 + l] = lq[k][l];
      Rm[i * 9 + k * 3 + l] = R[k][l];
      Sm[i * 9 + k * 3 + l] = S[k][l];
    }
}

// ---------- kernel 2: T = beta @ S  and column sums of beta (fused) ----------
// Each block owns 8 rows of beta; while streaming beta it also accumulates the
// 8-row partial column sums and atomicAdds them into cs (zeroed via memset).

__global__ void bmm_kernel(const float* __restrict__ beta, const float* __restrict__ S,
                           float* __restrict__ T, float* __restrict__ cs, int N) {
  const int ROWS = 8;
  int i0 = blockIdx.x * ROWS;
  int tid = threadIdx.x;
  float acc[ROWS][9];
#pragma unroll
  for (int r = 0; r < ROWS; ++r)
#pragma unroll
    for (int k = 0; k < 9; ++k) acc[r][k] = 0.f;

  for (int jt = 0; jt < N; jt += 256) {
    int j = jt + tid;
    if (j < N) {
      float sv[9];
#pragma unroll
      for (int k = 0; k < 9; ++k) sv[k] = S[j * 9 + k];
      float colp = 0.f;
#pragma unroll
      for (int r = 0; r < ROWS; ++r) {
        int row = i0 + r;
        if (row < N) {
          float b = beta[(size_t)row * N + j];
          colp += b;
#pragma unroll
          for (int k = 0; k < 9; ++k) acc[r][k] = fmaf(b, sv[k], acc[r][k]);
        }
      }
      atomicAdd(&cs[j], colp);
    }
  }

  __shared__ float red[4][9];
  for (int r = 0; r < ROWS; ++r) {
    float part[9];
#pragma unroll
    for (int k = 0; k < 9; ++k) {
      float x = acc[r][k];
#pragma unroll
      for (int o = 32; o > 0; o >>= 1) x += __shfl_down(x, o, 64);
      part[k] = x;
    }
    if ((tid & 63) == 0) {
#pragma unroll
      for (int k = 0; k < 9; ++k) red[tid >> 6][k] = part[k];
    }
    __syncthreads();
    if (tid == 0 && (i0 + r) < N) {
#pragma unroll
      for (int k = 0; k < 9; ++k)
        T[(i0 + r) * 9 + k] = red[0][k] + red[1][k] + red[2][k] + red[3][k];
    }
    __syncthreads();
  }
}

// ---------- kernel 3: Lambda_o moments + assemble M + Jacobi eigh (fused) ----------
// Block n: 256 threads reduce softmax moments over V; thread 0 then assembles
// M for i=n, runs the 3x3 eigensolver, and writes both outputs.

__global__ void lo_finalize_kernel(const float* __restrict__ mu, const float* __restrict__ W,
                                   const float* __restrict__ Lp, const float* __restrict__ Lq,
                                   const float* __restrict__ Rm, const float* __restrict__ T,
                                   const float* __restrict__ cs, float* __restrict__ out,
                                   int N, int V) {
  int n = blockIdx.x;
  int tid = threadIdx.x;
  float m0 = mu[n * 3 + 0], m1 = mu[n * 3 + 1], m2 = mu[n * 3 + 2];
  float se = 0.f, a0 = 0.f, a1 = 0.f, a2 = 0.f;
  float s00 = 0.f, s01 = 0.f, s02 = 0.f, s11 = 0.f, s12 = 0.f, s22 = 0.f;
  for (int v = tid; v < V; v += 256) {
    float w0 = W[v * 3 + 0], w1 = W[v * 3 + 1], w2 = W[v * 3 + 2];
    float l = fmaf(m0, w0, fmaf(m1, w1, m2 * w2));
    // logits bounded (|mu|,|w| small) -> no max-subtraction needed.
    float e = __expf(l);
    se += e;
    float ew0 = e * w0, ew1 = e * w1, ew2 = e * w2;
    a0 += ew0; a1 += ew1; a2 += ew2;
    s00 = fmaf(ew0, w0, s00); s01 = fmaf(ew0, w1, s01); s02 = fmaf(ew0, w2, s02);
    s11 = fmaf(ew1, w1, s11); s12 = fmaf(ew1, w2, s12); s22 = fmaf(ew2, w2, s22);
  }
  float vals[10] = {se, a0, a1, a2, s00, s01, s02, s11, s12, s22};
  __shared__ float sred[4][10];
#pragma unroll
  for (int k = 0; k < 10; ++k) {
    float x = vals[k];
#pragma unroll
    for (int o = 32; o > 0; o >>= 1) x += __shfl_down(x, o, 64);
    if ((tid & 63) == 0) sred[tid >> 6][k] = x;
  }
  __syncthreads();
  if (tid != 0) return;

  float tot[10];
#pragma unroll
  for (int k = 0; k < 10; ++k)
    tot[k] = sred[0][k] + sred[1][k] + sred[2][k] + sred[3][k];
  float inv = 1.0f / tot[0];
  float mw0 = tot[1] * inv, mw1 = tot[2] * inv, mw2 = tot[3] * inv;
  float Lo[3][3];
  Lo[0][0] = tot[4] * inv - mw0 * mw0 + EPSV;
  Lo[0][1] = Lo[1][0] = tot[5] * inv - mw0 * mw1;
  Lo[0][2] = Lo[2][0] = tot[6] * inv - mw0 * mw2;
  Lo[1][1] = tot[7] * inv - mw1 * mw1 + EPSV;
  Lo[1][2] = Lo[2][1] = tot[8] * inv - mw1 * mw2;
  Lo[2][2] = tot[9] * inv - mw2 * mw2 + EPSV;

  int i = n;
  float R[3][3], Tm[3][3], M[3][3];
#pragma unroll
  for (int k = 0; k < 3; ++k)
#pragma unroll
    for (int l = 0; l < 3; ++l) {
      R[k][l] = Rm[i * 9 + k * 3 + l];
      Tm[k][l] = T[i * 9 + k * 3 + l];
    }
  float t1[3][3], Rt[3][3], Min[3][3];
  mm3(R, Tm, t1);
#pragma unroll
  for (int k = 0; k < 3; ++k)
#pragma unroll
    for (int l = 0; l < 3; ++l) Rt[k][l] = R[l][k];
  mm3(t1, Rt, Min);
  float c = cs[i];
#pragma unroll
  for (int k = 0; k < 3; ++k)
#pragma unroll
    for (int l = 0; l < 3; ++l)
      M[k][l] = Lp[i * 9 + k * 3 + l] + Lo[k][l] + Min[k][l] + c * Lq[i * 9 + k * 3 + l];
  // symmetrize
#pragma unroll
  for (int k = 0; k < 3; ++k)
#pragma unroll
    for (int l = 0; l < 3; ++l) {
      if (l > k) {
        float v = 0.5f * (M[k][l] + M[l][k]);
        M[k][l] = v; M[l][k] = v;
      }
    }
  // non-finite -> identity entries
#pragma unroll
  for (int k = 0; k < 3; ++k)
#pragma unroll
    for (int l = 0; l < 3; ++l)
      if (!finitef(M[k][l])) M[k][l] = (k == l) ? 1.0f : 0.0f;
  M[0][0] += MINEIG; M[1][1] += MINEIG; M[2][2] += MINEIG;

  // cyclic Jacobi, 12 sweeps
  float A[3][3], Vv[3][3] = {{1, 0, 0}, {0, 1, 0}, {0, 0, 1}};
#pragma unroll
  for (int k = 0; k < 3; ++k)
#pragma unroll
    for (int l = 0; l < 3; ++l) A[k][l] = M[k][l];
  for (int sweep = 0; sweep < 12; ++sweep) {
    jrot<0, 1>(A, Vv);
    jrot<0, 2>(A, Vv);
    jrot<1, 2>(A, Vv);
  }
  float wc[3], wi[3];
#pragma unroll
  for (int k = 0; k < 3; ++k) {
    wc[k] = fmaxf(A[k][k], MINEIG);
    wi[k] = 1.0f / wc[k];
  }
#pragma unroll
  for (int k = 0; k < 3; ++k)
#pragma unroll
    for (int l = 0; l < 3; ++l) {
      float mpd = Vv[k][0] * wc[0] * Vv[l][0] + Vv[k][1] * wc[1] * Vv[l][1] +
                  Vv[k][2] * wc[2] * Vv[l][2];
      float mnv = Vv[k][0] * wi[0] * Vv[l][0] + Vv[k][1] * wi[1] * Vv[l][1] +
                  Vv[k][2] * wi[2] * Vv[l][2];
      out[i * 9 + k * 3 + l] = mpd;
      out[(size_t)N * 9 + i * 9 + k * 3 + l] = mnv;
    }
}

// ---------- launcher ----------

extern "C" void kernel_launch(void* const* d_in, const int* in_sizes, int n_in,
                              void* d_out, int out_size, void* d_ws, size_t ws_size,
                              hipStream_t stream) {
  const float* Sp = (const float*)d_in[0];
  const float* Sq = (const float*)d_in[1];
  const float* phi = (const float*)d_in[2];
  const float* beta = (const float*)d_in[3];
  const float* mu = (const float*)d_in[4];
  const float* W = (const float*)d_in[5];
  const float* gen = (const float*)d_in[6];
  float* out = (float*)d_out;

  const int N = in_sizes[2] / 3;   // phi is (B,N,3), B=1
  const int V = in_sizes[5] / 3;   // W_out is (V,3)

  float* ws = (float*)d_ws;
  float* Lp = ws;                // N*9
  float* Lq = Lp + (size_t)N * 9;
  float* Rm = Lq + (size_t)N * 9;
  float* Sm = Rm + (size_t)N * 9;
  float* T  = Sm + (size_t)N * 9;
  float* cs = T + (size_t)N * 9;  // N

  int nb = (N + 255) / 256;
  hipMemsetAsync(cs, 0, (size_t)N * sizeof(float), stream);
  prep_kernel<<<nb, 256, 0, stream>>>(Sp, Sq, phi, gen, Lp, Lq, Rm, Sm, N);
  bmm_kernel<<<(N + 7) / 8, 256, 0, stream>>>(beta, Sm, T, cs, N);
  lo_finalize_kernel<<<N, 256, 0, stream>>>(mu, W, Lp, Lq, Rm, T, cs, out, N, V);
}

// Round 3
// 128.527 us; speedup vs baseline: 4.9738x; 1.2157x over previous
//
#include <hip/hip_runtime.h>
#include <math.h>

#define EPSV 1e-6f
#define MINEIG 1e-4f

// ---------- small 3x3 helpers (all in registers) ----------

__device__ __forceinline__ void mm3(const float a[3][3], const float b[3][3], float c[3][3]) {
#pragma unroll
  for (int i = 0; i < 3; ++i)
#pragma unroll
    for (int j = 0; j < 3; ++j)
      c[i][j] = fmaf(a[i][0], b[0][j], fmaf(a[i][1], b[1][j], a[i][2] * b[2][j]));
}

__device__ __forceinline__ void inv3(const float a[3][3], float inv[3][3]) {
  float c00 = a[1][1] * a[2][2] - a[1][2] * a[2][1];
  float c01 = -(a[1][0] * a[2][2] - a[1][2] * a[2][0]);
  float c02 = a[1][0] * a[2][1] - a[1][1] * a[2][0];
  float det = a[0][0] * c00 + a[0][1] * c01 + a[0][2] * c02;
  float id = 1.0f / det;
  inv[0][0] = c00 * id;
  inv[0][1] = (a[0][2] * a[2][1] - a[0][1] * a[2][2]) * id;
  inv[0][2] = (a[0][1] * a[1][2] - a[0][2] * a[1][1]) * id;
  inv[1][0] = c01 * id;
  inv[1][1] = (a[0][0] * a[2][2] - a[0][2] * a[2][0]) * id;
  inv[1][2] = (a[0][2] * a[1][0] - a[0][0] * a[1][2]) * id;
  inv[2][0] = c02 * id;
  inv[2][1] = (a[0][1] * a[2][0] - a[0][0] * a[2][1]) * id;
  inv[2][2] = (a[0][0] * a[1][1] - a[0][1] * a[1][0]) * id;
}

// Matches reference _expm: scale by 2^-6, 12-term Taylor, 6 squarings.
__device__ void expm3(const float A[3][3], float E[3][3]) {
  float As[3][3], term[3][3], tmp[3][3];
#pragma unroll
  for (int i = 0; i < 3; ++i)
#pragma unroll
    for (int j = 0; j < 3; ++j) {
      As[i][j] = A[i][j] * (1.0f / 64.0f);
      term[i][j] = As[i][j];
      E[i][j] = ((i == j) ? 1.0f : 0.0f) + As[i][j];
    }
  for (int k = 2; k <= 12; ++k) {
    mm3(term, As, tmp);
    float r = 1.0f / (float)k;
#pragma unroll
    for (int i = 0; i < 3; ++i)
#pragma unroll
      for (int j = 0; j < 3; ++j) {
        term[i][j] = tmp[i][j] * r;
        E[i][j] += term[i][j];
      }
  }
  for (int s = 0; s < 6; ++s) {
    mm3(E, E, tmp);
#pragma unroll
    for (int i = 0; i < 3; ++i)
#pragma unroll
      for (int j = 0; j < 3; ++j) E[i][j] = tmp[i][j];
  }
}

template <int P, int Q>
__device__ __forceinline__ void jrot(float A[3][3], float V[3][3]) {
  float apq = A[P][Q];
  if (fabsf(apq) < 1e-20f) return;
  float theta = (A[Q][Q] - A[P][P]) / (2.0f * apq);
  float t = copysignf(1.0f, theta) / (fabsf(theta) + sqrtf(fmaf(theta, theta, 1.0f)));
  float c = 1.0f / sqrtf(fmaf(t, t, 1.0f));
  float s = t * c;
  float J[3][3] = {{1, 0, 0}, {0, 1, 0}, {0, 0, 1}};
  J[P][P] = c; J[Q][Q] = c; J[P][Q] = s; J[Q][P] = -s;
  float Jt[3][3];
#pragma unroll
  for (int i = 0; i < 3; ++i)
#pragma unroll
    for (int j = 0; j < 3; ++j) Jt[i][j] = J[j][i];
  float tmp[3][3], A2[3][3];
  mm3(A, J, tmp);
  mm3(Jt, tmp, A2);
#pragma unroll
  for (int i = 0; i < 3; ++i)
#pragma unroll
    for (int j = 0; j < 3; ++j) A[i][j] = A2[i][j];
  mm3(V, J, tmp);
#pragma unroll
  for (int i = 0; i < 3; ++i)
#pragma unroll
    for (int j = 0; j < 3; ++j) V[i][j] = tmp[i][j];
}

__device__ __forceinline__ bool finitef(float x) {
  return !(isnan(x) || isinf(x));
}

// ---------- kernel 1: per-n prep (blocks 0..N/256-1) + colsum partials ----------
// Colsum blocks also serve as beta's HBM first-touch so bmm reads L3-warm.

__global__ void prep_colsum_kernel(const float* __restrict__ Sp, const float* __restrict__ Sq,
                                   const float* __restrict__ phi, const float* __restrict__ gen,
                                   const float* __restrict__ beta,
                                   float* __restrict__ Lp, float* __restrict__ Lq,
                                   float* __restrict__ Rm, float* __restrict__ S12,
                                   float* __restrict__ pcs, int N) {
  int bid = blockIdx.x;
  int tid = threadIdx.x;
  int nPrep = N >> 8;  // N/256
  if (bid < nPrep) {
    int i = bid * 256 + tid;
    float a[3][3], lp[3][3], lq[3][3];
#pragma unroll
    for (int k = 0; k < 3; ++k)
#pragma unroll
      for (int l = 0; l < 3; ++l)
        a[k][l] = Sp[i * 9 + k * 3 + l] + ((k == l) ? EPSV : 0.0f);
    inv3(a, lp);
#pragma unroll
    for (int k = 0; k < 3; ++k)
#pragma unroll
      for (int l = 0; l < 3; ++l)
        a[k][l] = Sq[i * 9 + k * 3 + l] + ((k == l) ? EPSV : 0.0f);
    inv3(a, lq);

    float p0 = phi[i * 3 + 0], p1 = phi[i * 3 + 1], p2 = phi[i * 3 + 2];
    float A[3][3];
#pragma unroll
    for (int k = 0; k < 3; ++k)
#pragma unroll
      for (int l = 0; l < 3; ++l)
        A[k][l] = p0 * gen[0 + k * 3 + l] + p1 * gen[9 + k * 3 + l] + p2 * gen[18 + k * 3 + l];
    float R[3][3];
    expm3(A, R);
    // phi_mat exactly skew -> expm(-phi_mat) == R^T bitwise.
    float Rt[3][3];
#pragma unroll
    for (int k = 0; k < 3; ++k)
#pragma unroll
      for (int l = 0; l < 3; ++l) Rt[k][l] = R[l][k];
    float t1[3][3], S[3][3];
    mm3(lq, R, t1);
    mm3(Rt, t1, S);
#pragma unroll
    for (int k = 0; k < 3; ++k)
#pragma unroll
      for (int l = 0; l < 3; ++l) {
        Lp[i * 9 + k * 3 + l] = lp[k][l];
        Lq[i * 9 + k * 3 + l] = lq[k][l];
        Rm[i * 9 + k * 3 + l] = R[k][l];
        S12[i * 12 + k * 3 + l] = S[k][l];
      }
    S12[i * 12 + 9] = 0.f; S12[i * 12 + 10] = 0.f; S12[i * 12 + 11] = 0.f;
  } else {
    // colsum partial: 32 rows x 256 cols per block
    int cb = bid - nPrep;
    int nCT = N >> 8;          // column tiles of 256
    int rs = cb / nCT;         // row-split index, 0..N/32-1
    int ct = cb % nCT;
    int j = ct * 256 + tid;
    const float* bp = beta + (size_t)(rs * 32) * N + j;
    float s = 0.f;
#pragma unroll
    for (int r = 0; r < 32; ++r) s += bp[(size_t)r * N];
    pcs[(size_t)rs * N + j] = s;
  }
}

// ---------- kernel 2: T = beta @ S, one wave per output row ----------
// Lane-coalesced float4 beta loads; S12 (stride 12) as 3x float4 per column.
// Per-wave reduce of only 9 values -> no LDS, no barriers, no atomics.

__global__ void bmm_kernel(const float* __restrict__ beta, const float* __restrict__ S12,
                           float* __restrict__ T, int N) {
  int lane = threadIdx.x & 63;
  int w = threadIdx.x >> 6;
  int i = blockIdx.x * 4 + w;
  const float4* B4 = (const float4*)(beta + (size_t)i * N);
  const float4* S4 = (const float4*)S12;
  float acc[9];
#pragma unroll
  for (int k = 0; k < 9; ++k) acc[k] = 0.f;

  for (int jt = 0; jt < N; jt += 256) {
    int j = jt + lane * 4;
    float4 b = B4[j >> 2];
#pragma unroll
    for (int c = 0; c < 4; ++c) {
      float bc = (&b.x)[c];
      int sj = (j + c) * 3;
      float4 s0 = S4[sj + 0];
      float4 s1 = S4[sj + 1];
      float4 s2 = S4[sj + 2];
      acc[0] = fmaf(bc, s0.x, acc[0]);
      acc[1] = fmaf(bc, s0.y, acc[1]);
      acc[2] = fmaf(bc, s0.z, acc[2]);
      acc[3] = fmaf(bc, s0.w, acc[3]);
      acc[4] = fmaf(bc, s1.x, acc[4]);
      acc[5] = fmaf(bc, s1.y, acc[5]);
      acc[6] = fmaf(bc, s1.z, acc[6]);
      acc[7] = fmaf(bc, s1.w, acc[7]);
      acc[8] = fmaf(bc, s2.x, acc[8]);
    }
  }
#pragma unroll
  for (int k = 0; k < 9; ++k) {
    float x = acc[k];
#pragma unroll
    for (int o = 32; o > 0; o >>= 1) x += __shfl_down(x, o, 64);
    if (lane == 0) T[i * 9 + k] = x;
  }
}

// ---------- kernel 3: Lambda_o moments + cs fold + assemble M + Jacobi ----------

__global__ void lo_finalize_kernel(const float* __restrict__ mu, const float* __restrict__ W,
                                   const float* __restrict__ Lp, const float* __restrict__ Lq,
                                   const float* __restrict__ Rm, const float* __restrict__ T,
                                   const float* __restrict__ pcs, float* __restrict__ out,
                                   int N, int V) {
  int n = blockIdx.x;
  int tid = threadIdx.x;
  float m0 = mu[n * 3 + 0], m1 = mu[n * 3 + 1], m2 = mu[n * 3 + 2];
  float se = 0.f, a0 = 0.f, a1 = 0.f, a2 = 0.f;
  float s00 = 0.f, s01 = 0.f, s02 = 0.f, s11 = 0.f, s12 = 0.f, s22 = 0.f;
  const float4* W4 = (const float4*)W;
  // 4 vocab entries per lane-iter: 3 float4 = rows v..v+3
  for (int vb = tid; vb * 4 < V; vb += 256) {
    float4 f0 = W4[vb * 3 + 0];
    float4 f1 = W4[vb * 3 + 1];
    float4 f2 = W4[vb * 3 + 2];
    float wv[4][3] = {{f0.x, f0.y, f0.z}, {f0.w, f1.x, f1.y},
                      {f1.z, f1.w, f2.x}, {f2.y, f2.z, f2.w}};
#pragma unroll
    for (int c = 0; c < 4; ++c) {
      float w0 = wv[c][0], w1 = wv[c][1], w2 = wv[c][2];
      float l = fmaf(m0, w0, fmaf(m1, w1, m2 * w2));
      float e = __expf(l);
      se += e;
      float ew0 = e * w0, ew1 = e * w1, ew2 = e * w2;
      a0 += ew0; a1 += ew1; a2 += ew2;
      s00 = fmaf(ew0, w0, s00); s01 = fmaf(ew0, w1, s01); s02 = fmaf(ew0, w2, s02);
      s11 = fmaf(ew1, w1, s11); s12 = fmaf(ew1, w2, s12); s22 = fmaf(ew2, w2, s22);
    }
  }
  float vals[10] = {se, a0, a1, a2, s00, s01, s02, s11, s12, s22};
  __shared__ float sred[4][10];
  __shared__ float scs;
#pragma unroll
  for (int k = 0; k < 10; ++k) {
    float x = vals[k];
#pragma unroll
    for (int o = 32; o > 0; o >>= 1) x += __shfl_down(x, o, 64);
    if ((tid & 63) == 0) sred[tid >> 6][k] = x;
  }
  // wave 0 also folds the colsum partials (N/32 of them)
  if (tid < 64) {
    int RS = N >> 5;
    float x = 0.f;
    for (int r = tid; r < RS; r += 64) x += pcs[(size_t)r * N + n];
#pragma unroll
    for (int o = 32; o > 0; o >>= 1) x += __shfl_down(x, o, 64);
    if (tid == 0) scs = x;
  }
  __syncthreads();
  if (tid != 0) return;

  float tot[10];
#pragma unroll
  for (int k = 0; k < 10; ++k)
    tot[k] = sred[0][k] + sred[1][k] + sred[2][k] + sred[3][k];
  float inv = 1.0f / tot[0];
  float mw0 = tot[1] * inv, mw1 = tot[2] * inv, mw2 = tot[3] * inv;
  float Lo[3][3];
  Lo[0][0] = tot[4] * inv - mw0 * mw0 + EPSV;
  Lo[0][1] = Lo[1][0] = tot[5] * inv - mw0 * mw1;
  Lo[0][2] = Lo[2][0] = tot[6] * inv - mw0 * mw2;
  Lo[1][1] = tot[7] * inv - mw1 * mw1 + EPSV;
  Lo[1][2] = Lo[2][1] = tot[8] * inv - mw1 * mw2;
  Lo[2][2] = tot[9] * inv - mw2 * mw2 + EPSV;

  int i = n;
  float R[3][3], Tm[3][3], M[3][3];
#pragma unroll
  for (int k = 0; k < 3; ++k)
#pragma unroll
    for (int l = 0; l < 3; ++l) {
      R[k][l] = Rm[i * 9 + k * 3 + l];
      Tm[k][l] = T[i * 9 + k * 3 + l];
    }
  float t1[3][3], Rt[3][3], Min[3][3];
  mm3(R, Tm, t1);
#pragma unroll
  for (int k = 0; k < 3; ++k)
#pragma unroll
    for (int l = 0; l < 3; ++l) Rt[k][l] = R[l][k];
  mm3(t1, Rt, Min);
  float c = scs;
#pragma unroll
  for (int k = 0; k < 3; ++k)
#pragma unroll
    for (int l = 0; l < 3; ++l)
      M[k][l] = Lp[i * 9 + k * 3 + l] + Lo[k][l] + Min[k][l] + c * Lq[i * 9 + k * 3 + l];
#pragma unroll
  for (int k = 0; k < 3; ++k)
#pragma unroll
    for (int l = 0; l < 3; ++l) {
      if (l > k) {
        float v = 0.5f * (M[k][l] + M[l][k]);
        M[k][l] = v; M[l][k] = v;
      }
    }
#pragma unroll
  for (int k = 0; k < 3; ++k)
#pragma unroll
    for (int l = 0; l < 3; ++l)
      if (!finitef(M[k][l])) M[k][l] = (k == l) ? 1.0f : 0.0f;
  M[0][0] += MINEIG; M[1][1] += MINEIG; M[2][2] += MINEIG;

  float A[3][3], Vv[3][3] = {{1, 0, 0}, {0, 1, 0}, {0, 0, 1}};
#pragma unroll
  for (int k = 0; k < 3; ++k)
#pragma unroll
    for (int l = 0; l < 3; ++l) A[k][l] = M[k][l];
  for (int sweep = 0; sweep < 12; ++sweep) {
    jrot<0, 1>(A, Vv);
    jrot<0, 2>(A, Vv);
    jrot<1, 2>(A, Vv);
  }
  float wc[3], wi[3];
#pragma unroll
  for (int k = 0; k < 3; ++k) {
    wc[k] = fmaxf(A[k][k], MINEIG);
    wi[k] = 1.0f / wc[k];
  }
#pragma unroll
  for (int k = 0; k < 3; ++k)
#pragma unroll
    for (int l = 0; l < 3; ++l) {
      float mpd = Vv[k][0] * wc[0] * Vv[l][0] + Vv[k][1] * wc[1] * Vv[l][1] +
                  Vv[k][2] * wc[2] * Vv[l][2];
      float mnv = Vv[k][0] * wi[0] * Vv[l][0] + Vv[k][1] * wi[1] * Vv[l][1] +
                  Vv[k][2] * wi[2] * Vv[l][2];
      out[i * 9 + k * 3 + l] = mpd;
      out[(size_t)N * 9 + i * 9 + k * 3 + l] = mnv;
    }
}

// ---------- launcher ----------

extern "C" void kernel_launch(void* const* d_in, const int* in_sizes, int n_in,
                              void* d_out, int out_size, void* d_ws, size_t ws_size,
                              hipStream_t stream) {
  const float* Sp = (const float*)d_in[0];
  const float* Sq = (const float*)d_in[1];
  const float* phi = (const float*)d_in[2];
  const float* beta = (const float*)d_in[3];
  const float* mu = (const float*)d_in[4];
  const float* W = (const float*)d_in[5];
  const float* gen = (const float*)d_in[6];
  float* out = (float*)d_out;

  const int N = in_sizes[2] / 3;   // phi is (B,N,3), B=1
  const int V = in_sizes[5] / 3;   // W_out is (V,3)

  float* ws = (float*)d_ws;
  float* Lp = ws;                       // N*9
  float* Lq = Lp + (size_t)N * 9;       // N*9
  float* Rm = Lq + (size_t)N * 9;       // N*9
  float* S12 = Rm + (size_t)N * 9;      // N*12 (padded for float4)
  float* T = S12 + (size_t)N * 12;      // N*9
  float* pcs = T + (size_t)N * 9;       // (N/32)*N

  int nPrep = N / 256;
  int nColsum = (N / 32) * (N / 256);
  prep_colsum_kernel<<<nPrep + nColsum, 256, 0, stream>>>(Sp, Sq, phi, gen, beta,
                                                          Lp, Lq, Rm, S12, pcs, N);
  bmm_kernel<<<N / 4, 256, 0, stream>>>(beta, S12, T, N);
  lo_finalize_kernel<<<N, 256, 0, stream>>>(mu, W, Lp, Lq, Rm, T, pcs, out, N, V);
}

// Round 4
// 126.049 us; speedup vs baseline: 5.0716x; 1.0197x over previous
//
#include <hip/hip_runtime.h>
#include <math.h>

#define EPSV 1e-6f
#define MINEIG 1e-4f

// ---------- small 3x3 helpers (all in registers) ----------

__device__ __forceinline__ void mm3(const float a[3][3], const float b[3][3], float c[3][3]) {
#pragma unroll
  for (int i = 0; i < 3; ++i)
#pragma unroll
    for (int j = 0; j < 3; ++j)
      c[i][j] = fmaf(a[i][0], b[0][j], fmaf(a[i][1], b[1][j], a[i][2] * b[2][j]));
}

__device__ __forceinline__ void inv3(const float a[3][3], float inv[3][3]) {
  float c00 = a[1][1] * a[2][2] - a[1][2] * a[2][1];
  float c01 = -(a[1][0] * a[2][2] - a[1][2] * a[2][0]);
  float c02 = a[1][0] * a[2][1] - a[1][1] * a[2][0];
  float det = a[0][0] * c00 + a[0][1] * c01 + a[0][2] * c02;
  float id = 1.0f / det;
  inv[0][0] = c00 * id;
  inv[0][1] = (a[0][2] * a[2][1] - a[0][1] * a[2][2]) * id;
  inv[0][2] = (a[0][1] * a[1][2] - a[0][2] * a[1][1]) * id;
  inv[1][0] = c01 * id;
  inv[1][1] = (a[0][0] * a[2][2] - a[0][2] * a[2][0]) * id;
  inv[1][2] = (a[0][2] * a[1][0] - a[0][0] * a[1][2]) * id;
  inv[2][0] = c02 * id;
  inv[2][1] = (a[0][1] * a[2][0] - a[0][0] * a[2][1]) * id;
  inv[2][2] = (a[0][0] * a[1][1] - a[0][1] * a[1][0]) * id;
}

// Matches reference _expm: scale by 2^-6, 12-term Taylor, 6 squarings.
__device__ void expm3(const float A[3][3], float E[3][3]) {
  float As[3][3], term[3][3], tmp[3][3];
#pragma unroll
  for (int i = 0; i < 3; ++i)
#pragma unroll
    for (int j = 0; j < 3; ++j) {
      As[i][j] = A[i][j] * (1.0f / 64.0f);
      term[i][j] = As[i][j];
      E[i][j] = ((i == j) ? 1.0f : 0.0f) + As[i][j];
    }
  for (int k = 2; k <= 12; ++k) {
    mm3(term, As, tmp);
    float r = 1.0f / (float)k;
#pragma unroll
    for (int i = 0; i < 3; ++i)
#pragma unroll
      for (int j = 0; j < 3; ++j) {
        term[i][j] = tmp[i][j] * r;
        E[i][j] += term[i][j];
      }
  }
  for (int s = 0; s < 6; ++s) {
    mm3(E, E, tmp);
#pragma unroll
    for (int i = 0; i < 3; ++i)
#pragma unroll
      for (int j = 0; j < 3; ++j) E[i][j] = tmp[i][j];
  }
}

// Direct Jacobi rotation in plane (P,Q), RI = remaining index.
// Convention: A' = J^T A J with J[P][P]=J[Q][Q]=c, J[P][Q]=s, J[Q][P]=-s.
template <int P, int Q, int RI>
__device__ __forceinline__ void jrot(float A[3][3], float V[3][3]) {
  float apq = A[P][Q];
  if (fabsf(apq) < 1e-20f) return;
  float theta = (A[Q][Q] - A[P][P]) / (2.0f * apq);
  float t = copysignf(1.0f, theta) / (fabsf(theta) + sqrtf(fmaf(theta, theta, 1.0f)));
  float c = 1.0f / sqrtf(fmaf(t, t, 1.0f));
  float s = t * c;
  A[P][P] = A[P][P] - t * apq;
  A[Q][Q] = A[Q][Q] + t * apq;
  A[P][Q] = 0.f; A[Q][P] = 0.f;
  float arp = A[RI][P], arq = A[RI][Q];
  float nrp = c * arp - s * arq;
  float nrq = s * arp + c * arq;
  A[RI][P] = nrp; A[P][RI] = nrp;
  A[RI][Q] = nrq; A[Q][RI] = nrq;
#pragma unroll
  for (int i = 0; i < 3; ++i) {
    float vip = V[i][P], viq = V[i][Q];
    V[i][P] = c * vip - s * viq;
    V[i][Q] = s * vip + c * viq;
  }
}

__device__ __forceinline__ bool finitef(float x) {
  return !(isnan(x) || isinf(x));
}

// ---------- kernel 1: per-n prep (first N/256 blocks) + colsum partials ----------
// S written SoA: Ssoa[k*N + i] so bmm's loads are lane-contiguous.

__global__ void prep_colsum_kernel(const float* __restrict__ Sp, const float* __restrict__ Sq,
                                   const float* __restrict__ phi, const float* __restrict__ gen,
                                   const float* __restrict__ beta,
                                   float* __restrict__ Lp, float* __restrict__ Lq,
                                   float* __restrict__ Rm, float* __restrict__ Ssoa,
                                   float* __restrict__ pcs, int N) {
  int bid = blockIdx.x;
  int tid = threadIdx.x;
  int nPrep = N >> 8;  // N/256
  if (bid < nPrep) {
    int i = bid * 256 + tid;
    float a[3][3], lp[3][3], lq[3][3];
#pragma unroll
    for (int k = 0; k < 3; ++k)
#pragma unroll
      for (int l = 0; l < 3; ++l)
        a[k][l] = Sp[i * 9 + k * 3 + l] + ((k == l) ? EPSV : 0.0f);
    inv3(a, lp);
#pragma unroll
    for (int k = 0; k < 3; ++k)
#pragma unroll
      for (int l = 0; l < 3; ++l)
        a[k][l] = Sq[i * 9 + k * 3 + l] + ((k == l) ? EPSV : 0.0f);
    inv3(a, lq);

    float p0 = phi[i * 3 + 0], p1 = phi[i * 3 + 1], p2 = phi[i * 3 + 2];
    float A[3][3];
#pragma unroll
    for (int k = 0; k < 3; ++k)
#pragma unroll
      for (int l = 0; l < 3; ++l)
        A[k][l] = p0 * gen[0 + k * 3 + l] + p1 * gen[9 + k * 3 + l] + p2 * gen[18 + k * 3 + l];
    float R[3][3];
    expm3(A, R);
    // phi_mat exactly skew -> expm(-phi_mat) == R^T bitwise.
    float Rt[3][3];
#pragma unroll
    for (int k = 0; k < 3; ++k)
#pragma unroll
      for (int l = 0; l < 3; ++l) Rt[k][l] = R[l][k];
    float t1[3][3], S[3][3];
    mm3(lq, R, t1);
    mm3(Rt, t1, S);
#pragma unroll
    for (int k = 0; k < 3; ++k)
#pragma unroll
      for (int l = 0; l < 3; ++l) {
        Lp[i * 9 + k * 3 + l] = lp[k][l];
        Lq[i * 9 + k * 3 + l] = lq[k][l];
        Rm[i * 9 + k * 3 + l] = R[k][l];
        Ssoa[(k * 3 + l) * N + i] = S[k][l];   // SoA
      }
  } else {
    // colsum partial: 32 rows x 256 cols per block (also beta's HBM first-touch)
    int cb = bid - nPrep;
    int nCT = N >> 8;
    int rs = cb / nCT;
    int ct = cb % nCT;
    int j = ct * 256 + tid;
    const float* bp = beta + (size_t)(rs * 32) * N + j;
    float s = 0.f;
#pragma unroll
    for (int r = 0; r < 32; ++r) s += bp[(size_t)r * N];
    pcs[(size_t)rs * N + j] = s;
  }
}

// ---------- kernel 2: T = beta @ S, one wave per output row, SoA S ----------

__global__ void bmm_kernel(const float* __restrict__ beta, const float* __restrict__ Ssoa,
                           float* __restrict__ T, int N) {
  int lane = threadIdx.x & 63;
  int w = threadIdx.x >> 6;
  int i = blockIdx.x * 4 + w;
  const float4* B4 = (const float4*)(beta + (size_t)i * N);
  float acc[9];
#pragma unroll
  for (int k = 0; k < 9; ++k) acc[k] = 0.f;

  for (int jt = 0; jt < N; jt += 256) {
    int q = (jt >> 2) + lane;          // float4 index, lane-contiguous
    float4 b = B4[q];
    float4 sv[9];
#pragma unroll
    for (int k = 0; k < 9; ++k) sv[k] = ((const float4*)(Ssoa + k * N))[q];
#pragma unroll
    for (int k = 0; k < 9; ++k) {
      acc[k] = fmaf(b.x, sv[k].x, acc[k]);
      acc[k] = fmaf(b.y, sv[k].y, acc[k]);
      acc[k] = fmaf(b.z, sv[k].z, acc[k]);
      acc[k] = fmaf(b.w, sv[k].w, acc[k]);
    }
  }
#pragma unroll
  for (int k = 0; k < 9; ++k) {
    float x = acc[k];
#pragma unroll
    for (int o = 32; o > 0; o >>= 1) x += __shfl_down(x, o, 64);
    if (lane == 0) T[i * 9 + k] = x;
  }
}

// ---------- kernel 3: Lambda_o softmax moments, 4 n per block ----------

__global__ void lo_kernel(const float* __restrict__ mu, const float* __restrict__ W,
                          float* __restrict__ Lo, int V) {
  int n0 = blockIdx.x * 4;
  int tid = threadIdx.x;
  float m[4][3];
#pragma unroll
  for (int j = 0; j < 4; ++j) {
    m[j][0] = mu[(n0 + j) * 3 + 0];
    m[j][1] = mu[(n0 + j) * 3 + 1];
    m[j][2] = mu[(n0 + j) * 3 + 2];
  }
  float acc[4][10];
#pragma unroll
  for (int j = 0; j < 4; ++j)
#pragma unroll
    for (int k = 0; k < 10; ++k) acc[j][k] = 0.f;

  const float4* W4 = (const float4*)W;
  for (int vb = tid; vb * 4 < V; vb += 256) {
    float4 f0 = W4[vb * 3 + 0];
    float4 f1 = W4[vb * 3 + 1];
    float4 f2 = W4[vb * 3 + 2];
    float wv[4][3] = {{f0.x, f0.y, f0.z}, {f0.w, f1.x, f1.y},
                      {f1.z, f1.w, f2.x}, {f2.y, f2.z, f2.w}};
#pragma unroll
    for (int c = 0; c < 4; ++c) {
      float w0 = wv[c][0], w1 = wv[c][1], w2 = wv[c][2];
      // pairwise products shared across the 4 n
      float p00 = w0 * w0, p01 = w0 * w1, p02 = w0 * w2;
      float p11 = w1 * w1, p12 = w1 * w2, p22 = w2 * w2;
#pragma unroll
      for (int j = 0; j < 4; ++j) {
        float l = fmaf(m[j][0], w0, fmaf(m[j][1], w1, m[j][2] * w2));
        float e = __expf(l);
        acc[j][0] += e;
        acc[j][1] = fmaf(e, w0, acc[j][1]);
        acc[j][2] = fmaf(e, w1, acc[j][2]);
        acc[j][3] = fmaf(e, w2, acc[j][3]);
        acc[j][4] = fmaf(e, p00, acc[j][4]);
        acc[j][5] = fmaf(e, p01, acc[j][5]);
        acc[j][6] = fmaf(e, p02, acc[j][6]);
        acc[j][7] = fmaf(e, p11, acc[j][7]);
        acc[j][8] = fmaf(e, p12, acc[j][8]);
        acc[j][9] = fmaf(e, p22, acc[j][9]);
      }
    }
  }

  __shared__ float sred[4][40];
#pragma unroll
  for (int j = 0; j < 4; ++j)
#pragma unroll
    for (int k = 0; k < 10; ++k) {
      float x = acc[j][k];
#pragma unroll
      for (int o = 32; o > 0; o >>= 1) x += __shfl_down(x, o, 64);
      if ((tid & 63) == 0) sred[tid >> 6][j * 10 + k] = x;
    }
  __syncthreads();
  if (tid < 4) {
    int j = tid;
    float tot[10];
#pragma unroll
    for (int k = 0; k < 10; ++k)
      tot[k] = sred[0][j * 10 + k] + sred[1][j * 10 + k] +
               sred[2][j * 10 + k] + sred[3][j * 10 + k];
    float inv = 1.0f / tot[0];
    float mw0 = tot[1] * inv, mw1 = tot[2] * inv, mw2 = tot[3] * inv;
    float* o = Lo + (n0 + j) * 9;
    o[0] = tot[4] * inv - mw0 * mw0 + EPSV;
    float v01 = tot[5] * inv - mw0 * mw1;
    float v02 = tot[6] * inv - mw0 * mw2;
    o[1] = v01; o[3] = v01;
    o[2] = v02; o[6] = v02;
    o[4] = tot[7] * inv - mw1 * mw1 + EPSV;
    float v12 = tot[8] * inv - mw1 * mw2;
    o[5] = v12; o[7] = v12;
    o[8] = tot[9] * inv - mw2 * mw2 + EPSV;
  }
}

// ---------- kernel 4: thread-per-n finalize: assemble M, Jacobi, outputs ----------

__global__ void finalize_kernel(const float* __restrict__ Lp, const float* __restrict__ Lq,
                                const float* __restrict__ Rm, const float* __restrict__ Lo,
                                const float* __restrict__ T, const float* __restrict__ pcs,
                                float* __restrict__ out, int N) {
  int i = blockIdx.x * blockDim.x + threadIdx.x;
  if (i >= N) return;

  // fold colsum partials: coalesced (fixed r -> consecutive i)
  float c = 0.f;
  int RS = N >> 5;
  for (int r = 0; r < RS; ++r) c += pcs[(size_t)r * N + i];

  float R[3][3], Tm[3][3], M[3][3];
#pragma unroll
  for (int k = 0; k < 3; ++k)
#pragma unroll
    for (int l = 0; l < 3; ++l) {
      R[k][l] = Rm[i * 9 + k * 3 + l];
      Tm[k][l] = T[i * 9 + k * 3 + l];
    }
  float t1[3][3], Rt[3][3], Min[3][3];
  mm3(R, Tm, t1);
#pragma unroll
  for (int k = 0; k < 3; ++k)
#pragma unroll
    for (int l = 0; l < 3; ++l) Rt[k][l] = R[l][k];
  mm3(t1, Rt, Min);
#pragma unroll
  for (int k = 0; k < 3; ++k)
#pragma unroll
    for (int l = 0; l < 3; ++l)
      M[k][l] = Lp[i * 9 + k * 3 + l] + Lo[i * 9 + k * 3 + l] + Min[k][l] +
                c * Lq[i * 9 + k * 3 + l];
#pragma unroll
  for (int k = 0; k < 3; ++k)
#pragma unroll
    for (int l = 0; l < 3; ++l) {
      if (l > k) {
        float v = 0.5f * (M[k][l] + M[l][k]);
        M[k][l] = v; M[l][k] = v;
      }
    }
#pragma unroll
  for (int k = 0; k < 3; ++k)
#pragma unroll
    for (int l = 0; l < 3; ++l)
      if (!finitef(M[k][l])) M[k][l] = (k == l) ? 1.0f : 0.0f;
  M[0][0] += MINEIG; M[1][1] += MINEIG; M[2][2] += MINEIG;

  float A[3][3], Vv[3][3] = {{1, 0, 0}, {0, 1, 0}, {0, 0, 1}};
#pragma unroll
  for (int k = 0; k < 3; ++k)
#pragma unroll
    for (int l = 0; l < 3; ++l) A[k][l] = M[k][l];
  for (int sweep = 0; sweep < 8; ++sweep) {
    jrot<0, 1, 2>(A, Vv);
    jrot<0, 2, 1>(A, Vv);
    jrot<1, 2, 0>(A, Vv);
  }
  float wc[3], wi[3];
#pragma unroll
  for (int k = 0; k < 3; ++k) {
    wc[k] = fmaxf(A[k][k], MINEIG);
    wi[k] = 1.0f / wc[k];
  }
#pragma unroll
  for (int k = 0; k < 3; ++k)
#pragma unroll
    for (int l = 0; l < 3; ++l) {
      float mpd = Vv[k][0] * wc[0] * Vv[l][0] + Vv[k][1] * wc[1] * Vv[l][1] +
                  Vv[k][2] * wc[2] * Vv[l][2];
      float mnv = Vv[k][0] * wi[0] * Vv[l][0] + Vv[k][1] * wi[1] * Vv[l][1] +
                  Vv[k][2] * wi[2] * Vv[l][2];
      out[i * 9 + k * 3 + l] = mpd;
      out[(size_t)N * 9 + i * 9 + k * 3 + l] = mnv;
    }
}

// ---------- launcher ----------

extern "C" void kernel_launch(void* const* d_in, const int* in_sizes, int n_in,
                              void* d_out, int out_size, void* d_ws, size_t ws_size,
                              hipStream_t stream) {
  const float* Sp = (const float*)d_in[0];
  const float* Sq = (const float*)d_in[1];
  const float* phi = (const float*)d_in[2];
  const float* beta = (const float*)d_in[3];
  const float* mu = (const float*)d_in[4];
  const float* W = (const float*)d_in[5];
  const float* gen = (const float*)d_in[6];
  float* out = (float*)d_out;

  const int N = in_sizes[2] / 3;   // phi is (B,N,3), B=1
  const int V = in_sizes[5] / 3;   // W_out is (V,3)

  float* ws = (float*)d_ws;
  float* Lp = ws;                        // N*9
  float* Lq = Lp + (size_t)N * 9;        // N*9
  float* Rm = Lq + (size_t)N * 9;        // N*9
  float* Ssoa = Rm + (size_t)N * 9;      // N*9 (SoA)
  float* T = Ssoa + (size_t)N * 9;       // N*9
  float* Lo = T + (size_t)N * 9;         // N*9
  float* pcs = Lo + (size_t)N * 9;       // (N/32)*N

  int nPrep = N / 256;
  int nColsum = (N / 32) * (N / 256);
  prep_colsum_kernel<<<nPrep + nColsum, 256, 0, stream>>>(Sp, Sq, phi, gen, beta,
                                                          Lp, Lq, Rm, Ssoa, pcs, N);
  lo_kernel<<<N / 4, 256, 0, stream>>>(mu, W, Lo, V);
  bmm_kernel<<<N / 4, 256, 0, stream>>>(beta, Ssoa, T, N);
  finalize_kernel<<<N / 256, 256, 0, stream>>>(Lp, Lq, Rm, Lo, T, pcs, out, N);
}